// Round 17
// baseline (236.080 us; speedup 1.0000x reference)
//
#include <hip/hip_runtime.h>

typedef __bf16 bf16;
typedef bf16 bf16x2 __attribute__((ext_vector_type(2)));
typedef bf16 bf16x8 __attribute__((ext_vector_type(8)));
typedef float f32x4 __attribute__((ext_vector_type(4)));

__device__ __forceinline__ void gload16(const bf16* g, bf16* l) {
  __builtin_amdgcn_global_load_lds((const __attribute__((address_space(1))) void*)g,
                                   (__attribute__((address_space(3))) void*)l, 16, 0, 0);
}

// ---------- pack x [128][2048][16][4] f32 -> bf16 channel-last ----------
template <bool FULL>
__global__ __launch_bounds__(256) void pack_x(const float* __restrict__ x, bf16* __restrict__ dstbuf) {
  __shared__ float tile[64 * 65];
  const int b = blockIdx.x, cb = blockIdx.y;
  const int t = threadIdx.x;
  const float* src = x + ((size_t)b * 2048 + cb * 64) * 64;
  #pragma unroll
  for (int p = 0; p < 16; ++p) {
    int idx = t + p * 256;
    tile[(idx >> 6) * 65 + (idx & 63)] = src[idx];
  }
  __syncthreads();
  if constexpr (FULL) {
    bf16* dst = dstbuf + (size_t)b * 131072 + cb * 64;
    #pragma unroll
    for (int p = 0; p < 8; ++p) {
      int idx = t + p * 256;
      int dhw = idx >> 5;
      int cl2 = (idx & 31) * 2;
      bf16x2 v;
      v.x = (bf16)tile[cl2 * 65 + dhw];
      v.y = (bf16)tile[(cl2 + 1) * 65 + dhw];
      *(bf16x2*)(dst + (size_t)dhw * 2048 + cl2) = v;
    }
  } else {
    bf16* dst = dstbuf + ((size_t)b * 32) * 2048 + cb * 64;
    const int cl2 = (t & 31) * 2, mr0 = t >> 5;
    #pragma unroll
    for (int p = 0; p < 4; ++p) {
      int mrow = mr0 + p * 8;
      int dd = mrow >> 2, hw = mrow & 3;
      int sdhw = dd * 8 + hw;
      bf16x2 v;
      v.x = (bf16)tile[cl2 * 65 + sdhw];
      v.y = (bf16)tile[(cl2 + 1) * 65 + sdhw];
      *(bf16x2*)(dst + (size_t)mrow * 2048 + cl2) = v;
    }
  }
}

// ---------- head0 weights -> Bh [16][8192] bf16 ----------
__global__ __launch_bounds__(256) void pack_w0(const float* __restrict__ lw0,
                                               const float* __restrict__ cw0,
                                               bf16* __restrict__ Bh) {
  int idx = blockIdx.x * 256 + threadIdx.x;
  int n = idx >> 13, k = idx & 8191;
  int hw = k >> 11, c = k & 2047;
  float v = 0.f;
  if (n < 10) {
    int kd = n / 5, j = n % 5;
    const float* w = (j < 2) ? (lw0 + j * 16384) : (cw0 + (j - 2) * 16384);
    v = w[c * 8 + kd * 4 + hw];
  }
  Bh[idx] = (bf16)v;
}

// ---------- head0 GEMM: M=2048, N=16, K=8192, split-K 8 ----------
__global__ __launch_bounds__(256) void head0_gemm(const bf16* __restrict__ xcl,
                                                  const bf16* __restrict__ Bh,
                                                  float* __restrict__ P) {
  __shared__ bf16 ldsA[64 * 64];
  __shared__ bf16 ldsB[16 * 64];
  const int bm = blockIdx.x, ks = blockIdx.y;
  const int tid = threadIdx.x;
  const int wv = tid >> 6, lane = tid & 63, r = lane & 15, g = lane >> 4;
  f32x4 acc = {0.f, 0.f, 0.f, 0.f};
  for (int k0 = 0; k0 < 1024; k0 += 64) {
    #pragma unroll
    for (int q = 0; q < 2; ++q) {
      int idx = tid + q * 256;
      int row = idx >> 3, cg = idx & 7;
      gload16(xcl + (size_t)(bm * 64 + row) * 8192 + ks * 1024 + k0 + (cg ^ (row & 7)) * 8,
              ldsA + idx * 8);
    }
    if (tid < 128) {
      int row = tid >> 3, cg = tid & 7;
      gload16(Bh + (size_t)row * 8192 + ks * 1024 + k0 + (cg ^ (row & 7)) * 8,
              ldsB + tid * 8);
    }
    __syncthreads();
    #pragma unroll
    for (int ks2 = 0; ks2 < 2; ++ks2) {
      int rowa = wv * 16 + r;
      bf16x8 af = *(const bf16x8*)(ldsA + rowa * 64 + ((ks2 * 4 + g) ^ (rowa & 7)) * 8);
      bf16x8 bf_ = *(const bf16x8*)(ldsB + r * 64 + ((ks2 * 4 + g) ^ (r & 7)) * 8);
      acc = __builtin_amdgcn_mfma_f32_16x16x32_bf16(af, bf_, acc, 0, 0, 0);
    }
    __syncthreads();
  }
  const int m = bm * 64 + wv * 16 + g * 4;
  #pragma unroll
  for (int jr = 0; jr < 4; ++jr)
    P[(size_t)(ks * 2048 + m + jr) * 16 + r] = acc[jr];
}

// ---------- head0 combine ----------
__global__ __launch_bounds__(128) void head0_combine(const float* __restrict__ P,
                                                     float* __restrict__ out) {
  const int b = blockIdx.x, t = threadIdx.x;
  if (t < 75) {
    int j = t / 15, d = t % 15;
    float s = 0.f;
    #pragma unroll
    for (int ks = 0; ks < 8; ++ks) {
      const float* pb = P + (size_t)(ks * 2048 + b * 16) * 16;
      s += pb[d * 16 + j] + pb[(d + 1) * 16 + 5 + j];
    }
    if (j < 2) out[b * 52 + j * 15 + d] = s;
    else       out[6656 + b * 78 + (j - 2) * 15 + d] = s;
  }
}

// ---------- f32 -> bf16 flat convert ----------
__global__ __launch_bounds__(256) void cvt_w1(const float* __restrict__ in, bf16* __restrict__ out, int n8) {
  int i = blockIdx.x * 256 + threadIdx.x;
  if (i < n8) {
    const float4* p = (const float4*)(in + (size_t)i * 8);
    float4 a = p[0], b = p[1];
    bf16x8 v = {(bf16)a.x, (bf16)a.y, (bf16)a.z, (bf16)a.w,
                (bf16)b.x, (bf16)b.y, (bf16)b.z, (bf16)b.w};
    *(bf16x8*)(out + (size_t)i * 8) = v;
  }
}

// ---------- w2 [cout][cin][27] f32 -> w2p [oCnt][27][cin] bf16 ----------
__global__ __launch_bounds__(256) void pack_w2(const float* __restrict__ w2, bf16* __restrict__ w2p,
                                               int oBase, int cin) {
  __shared__ float tile[64 * 27];
  const int orel = blockIdx.x, cb = blockIdx.y;
  const int o = oBase + orel;
  const float* src = w2 + ((size_t)o * cin + cb * 64) * 27;
  const int t = threadIdx.x;
  for (int idx = t; idx < 1728; idx += 256) tile[idx] = src[idx];
  __syncthreads();
  bf16* dst = w2p + (size_t)orel * 27 * cin + cb * 64;
  for (int idx = t; idx < 1728; idx += 256) {
    int tap = idx >> 6, cl = idx & 63;
    dst[(size_t)tap * cin + cl] = (bf16)tile[cl * 27 + tap];
  }
}

// ---------- generic bf16 MFMA GEMM (BK=64, scalarized W2M, proven) ----------
struct GP {
  const bf16* A; const bf16* B; bf16* O;
  int K;
  int ashb, asB, am1, as1, am2, as2;
  int oshb, osB, om1, os1, om2, os2, oOff;
  int lgCv, coutS, oCol0, lgCin;
};

template <int FM, int FN, bool W2M>
__global__ __launch_bounds__(256) void gemm_bf(GP p) {
  constexpr int BM = FM * 32, BN = FN * 32;
  __shared__ bf16 lds[(BM + BN) * 64];
  bf16* ldsA = lds;
  bf16* ldsB = lds + BM * 64;
  const int tid = threadIdx.x;
  const int bm = blockIdx.x, bn = blockIdx.y;

  int aBase[BM / 32], aL[BM / 32];
  #pragma unroll
  for (int q = 0; q < BM / 32; ++q) {
    int idx = tid + q * 256;
    int row = idx >> 3, cg = idx & 7;
    int m = bm * BM + row;
    aBase[q] = (m >> p.ashb) * p.asB + ((m >> 2) & p.am1) * p.as1 + (m & p.am2) * p.as2;
    aL[q] = ((cg ^ row) & 7) * 8;
  }
  int opk[BN / 32];
  int bN[BN / 32], bL[BN / 32];
  int khkw0 = 0, khkw1 = 0, khkw2 = 0, khkw3 = 0;
  #pragma unroll
  for (int q = 0; q < BN / 32; ++q) {
    int idx = tid + q * 256;
    int row = idx >> 3, cg = idx & 7;
    int n = bn * BN + row;
    int sw = ((cg ^ row) & 7) * 8;
    if constexpr (W2M) {
      int op = n & ((1 << p.lgCv) - 1);
      opk[q] = (op * 27 << p.lgCin) + sw;
      bN[q] = 0; bL[q] = 0;
    } else {
      bN[q] = n; bL[q] = sw; opk[q] = 0;
    }
  }
  if constexpr (W2M) {
    const int hwp = (bn * BN) >> p.lgCv;
    const int hp = hwp >> 1, wp = hwp & 1;
    khkw0 = ((1 - hp) * 3 + (1 - wp)) << p.lgCin;
    khkw1 = ((1 - hp) * 3 + (2 - wp)) << p.lgCin;
    khkw2 = ((2 - hp) * 3 + (1 - wp)) << p.lgCin;
    khkw3 = ((2 - hp) * 3 + (2 - wp)) << p.lgCin;
  }

  const int wv = tid >> 6, wm = wv >> 1, wn = wv & 1;
  const int lane = tid & 63, r = lane & 15, g = lane >> 4;

  f32x4 acc[FM][FN];
  const f32x4 zz = {0.f, 0.f, 0.f, 0.f};
  #pragma unroll
  for (int i = 0; i < FM; ++i)
    #pragma unroll
    for (int j = 0; j < FN; ++j) acc[i][j] = zz;

  for (int k0 = 0; k0 < p.K; k0 += 64) {
    #pragma unroll
    for (int q = 0; q < BM / 32; ++q) {
      int idx = tid + q * 256;
      gload16(p.A + aBase[q] + k0 + aL[q], ldsA + idx * 8);
    }
    if constexpr (W2M) {
      const int kd = k0 >> (p.lgCin + 2);
      const int hwsel = (k0 >> p.lgCin) & 3;
      const int c0 = k0 & ((1 << p.lgCin) - 1);
      int kk = (hwsel & 2) ? ((hwsel & 1) ? khkw3 : khkw2)
                           : ((hwsel & 1) ? khkw1 : khkw0);
      const int koff = (kd * 9 << p.lgCin) + kk + c0;
      #pragma unroll
      for (int q = 0; q < BN / 32; ++q) {
        int idx = tid + q * 256;
        gload16(p.B + opk[q] + koff, ldsB + idx * 8);
      }
    } else {
      #pragma unroll
      for (int q = 0; q < BN / 32; ++q) {
        int idx = tid + q * 256;
        gload16(p.B + (size_t)bN[q] * p.K + k0 + bL[q], ldsB + idx * 8);
      }
    }
    __syncthreads();
    #pragma unroll
    for (int ks = 0; ks < 2; ++ks) {
      bf16x8 af[FM], bfr[FN];
      #pragma unroll
      for (int i = 0; i < FM; ++i) {
        int row = wm * FM * 16 + i * 16 + r;
        int pcg = (ks * 4 + g) ^ (row & 7);
        af[i] = *(const bf16x8*)(ldsA + row * 64 + pcg * 8);
      }
      #pragma unroll
      for (int j = 0; j < FN; ++j) {
        int row = wn * FN * 16 + j * 16 + r;
        int pcg = (ks * 4 + g) ^ (row & 7);
        bfr[j] = *(const bf16x8*)(ldsB + row * 64 + pcg * 8);
      }
      #pragma unroll
      for (int i = 0; i < FM; ++i)
        #pragma unroll
        for (int j = 0; j < FN; ++j)
          acc[i][j] = __builtin_amdgcn_mfma_f32_16x16x32_bf16(af[i], bfr[j], acc[i][j], 0, 0, 0);
    }
    __syncthreads();
  }

  #pragma unroll
  for (int i = 0; i < FM; ++i) {
    #pragma unroll
    for (int j = 0; j < FN; ++j) {
      int ncol = bn * BN + wn * FN * 16 + j * 16 + r;
      int outcol = (ncol >> p.lgCv) * p.coutS + p.oCol0 + (ncol & ((1 << p.lgCv) - 1));
      #pragma unroll
      for (int jr = 0; jr < 4; ++jr) {
        int m = bm * BM + wm * FM * 16 + i * 16 + g * 4 + jr;
        int oa = (m >> p.oshb) * p.osB + ((m >> 2) & p.om1) * p.os1 + (m & p.om2) * p.os2 + p.oOff + outcol;
        p.O[oa] = (bf16)acc[i][j][jr];
      }
    }
  }
}

// ---------- g1: 32^2 tile, 2048 blocks = 8/CU, XCD-sliced along M (r16) ----------
__global__ __launch_bounds__(256) void gemm1b(const bf16* __restrict__ A,
                                              const bf16* __restrict__ B,
                                              bf16* __restrict__ O) {
  __shared__ bf16 lds[4096];
  bf16* ldsA = lds;
  bf16* ldsB = lds + 2048;
  const int tid = threadIdx.x;
  const int id = blockIdx.x;
  const int s = id >> 3;
  const int bm = (id & 7) * 16 + (s & 15);
  const int bn = s >> 4;

  const int row = tid >> 3, cg = tid & 7;
  const int sw = ((cg ^ row) & 7) * 8;
  const int m0 = bm * 32 + row;
  const int aOff = (m0 >> 5) * 131072 + ((m0 >> 2) & 7) * 16384 + (m0 & 3) * 2048 + sw;
  const int n0 = bn * 32 + row;
  const int bOff = n0 * 2048 + sw;

  const int wv = tid >> 6, wm = wv >> 1, wn = wv & 1;
  const int lane = tid & 63, r = lane & 15, g = lane >> 4;

  f32x4 acc = {0.f, 0.f, 0.f, 0.f};

  for (int k0 = 0; k0 < 2048; k0 += 64) {
    gload16(A + aOff + k0, ldsA + tid * 8);
    gload16(B + bOff + k0, ldsB + tid * 8);
    __syncthreads();
    #pragma unroll
    for (int ks = 0; ks < 2; ++ks) {
      int rowa = wm * 16 + r;
      int rowb = wn * 16 + r;
      bf16x8 af = *(const bf16x8*)(ldsA + rowa * 64 + (((ks * 4 + g) ^ rowa) & 7) * 8);
      bf16x8 bf_ = *(const bf16x8*)(ldsB + rowb * 64 + (((ks * 4 + g) ^ rowb) & 7) * 8);
      acc = __builtin_amdgcn_mfma_f32_16x16x32_bf16(af, bf_, acc, 0, 0, 0);
    }
    __syncthreads();
  }

  const int col = bn * 32 + wn * 16 + r;
  #pragma unroll
  for (int jr = 0; jr < 4; ++jr) {
    int m = bm * 32 + wm * 16 + g * 4 + jr;
    int oa = (m >> 5) * 20480 + ((m >> 2) & 7) * 2048 + (m & 3) * 512 + 2048 + col;
    O[oa] = (bf16)acc[jr];
  }
}

// ---------- g2 v2: 64^2 tile, 2 waves of 32x64 (FM=2,FN=4), XCD-swizzled ----------
// Same grid/addressing/swizzle as r12 champion; higher FLOP/LDS-byte (21.3 vs 16).
__global__ __launch_bounds__(128) void gemm2_v2(const bf16* __restrict__ A,
                                                const bf16* __restrict__ B,
                                                bf16* __restrict__ O) {
  __shared__ bf16 lds[8192];
  bf16* ldsA = lds;
  bf16* ldsB = lds + 4096;
  const int tid = threadIdx.x;          // 0..127
  const int id = blockIdx.x + (blockIdx.y << 4);
  const int s = id >> 3;
  const int bn = (id & 7) * 8 + (s & 7);
  const int bm = s >> 3;

  int aOff[4], bOff[4];
  #pragma unroll
  for (int q = 0; q < 4; ++q) {
    int idx = tid + q * 128;            // 0..511
    int row = idx >> 3, cg = idx & 7;
    int sw = ((cg ^ row) & 7) * 8;
    int m = bm * 64 + row;
    aOff[q] = (m >> 3) * 20480 + (m & 7) * 2048 + sw;
    int n = bn * 64 + row;
    bOff[q] = (n & 1023) * 13824 + sw;
  }
  const int hwp = (bn * 64) >> 10;
  const int hp = hwp >> 1, wp = hwp & 1;
  const int kk0 = ((1 - hp) * 3 + (1 - wp)) << 9;
  const int kk1 = ((1 - hp) * 3 + (2 - wp)) << 9;
  const int kk2 = ((2 - hp) * 3 + (1 - wp)) << 9;
  const int kk3 = ((2 - hp) * 3 + (2 - wp)) << 9;

  const int wv = tid >> 6;              // 0..1 (owns rows wv*32..wv*32+31)
  const int lane = tid & 63, r = lane & 15, g = lane >> 4;

  f32x4 acc[2][4];
  const f32x4 zz = {0.f, 0.f, 0.f, 0.f};
  #pragma unroll
  for (int i = 0; i < 2; ++i)
    #pragma unroll
    for (int j = 0; j < 4; ++j) acc[i][j] = zz;

  for (int k0 = 0; k0 < 6144; k0 += 64) {
    int kd = k0 >> 11, hws = (k0 >> 9) & 3, c0 = k0 & 511;
    int kk = (hws & 2) ? ((hws & 1) ? kk3 : kk2) : ((hws & 1) ? kk1 : kk0);
    int koff = kd * 4608 + kk + c0;
    #pragma unroll
    for (int q = 0; q < 4; ++q) {
      int idx = tid + q * 128;
      gload16(A + aOff[q] + k0, ldsA + idx * 8);
      gload16(B + bOff[q] + koff, ldsB + idx * 8);
    }
    __syncthreads();
    #pragma unroll
    for (int ks = 0; ks < 2; ++ks) {
      bf16x8 af[2], bfr[4];
      #pragma unroll
      for (int i = 0; i < 2; ++i) {
        int row = wv * 32 + i * 16 + r;
        int pcg = (ks * 4 + g) ^ (row & 7);
        af[i] = *(const bf16x8*)(ldsA + row * 64 + pcg * 8);
      }
      #pragma unroll
      for (int j = 0; j < 4; ++j) {
        int row = j * 16 + r;
        int pcg = (ks * 4 + g) ^ (row & 7);
        bfr[j] = *(const bf16x8*)(ldsB + row * 64 + pcg * 8);
      }
      #pragma unroll
      for (int i = 0; i < 2; ++i)
        #pragma unroll
        for (int j = 0; j < 4; ++j)
          acc[i][j] = __builtin_amdgcn_mfma_f32_16x16x32_bf16(af[i], bfr[j], acc[i][j], 0, 0, 0);
    }
    __syncthreads();
  }

  #pragma unroll
  for (int i = 0; i < 2; ++i) {
    #pragma unroll
    for (int j = 0; j < 4; ++j) {
      int col = bn * 64 + j * 16 + r;
      #pragma unroll
      for (int jr = 0; jr < 4; ++jr) {
        int rw = bm * 64 + wv * 32 + i * 16 + g * 4 + jr;
        O[(size_t)rw * 4096 + col] = (bf16)acc[i][j][jr];
      }
    }
  }
}

// ---------- detection heads: kernel (2,2,2) VALID ----------
template <typename T, bool XL>
__global__ __launch_bounds__(256)
void heads_k(const T* __restrict__ in, const float* __restrict__ wl,
             const float* __restrict__ wc, float* __restrict__ out,
             const int C, const int dcnt, const int sB, const int sD,
             const int sHW, const int sC, const int loff, const int coff) {
  const int tid = threadIdx.x;
  const int blk = blockIdx.x;
  const int b = blk / dcnt, d = blk - b * dcnt;
  float a0 = 0, a1 = 0, c0 = 0, c1 = 0, c2 = 0;
  const int C8 = C * 8;
  if constexpr (XL) {
    const int hw = tid & 3, kd = (tid >> 2) & 1, cb = tid >> 3;
    const int base = b * sB + (d + kd) * sD + hw * sHW;
    const int wb = kd * 4 + hw;
    for (int i = 0; i < C / 32; ++i) {
      const int c = cb + i * 32;
      const float v = (float)in[base + c * sC];
      const int wi = c * 8 + wb;
      a0 += v * wl[wi];  a1 += v * wl[C8 + wi];
      c0 += v * wc[wi];  c1 += v * wc[C8 + wi];  c2 += v * wc[2 * C8 + wi];
    }
  } else {
    for (int c = tid; c < C; c += 256) {
      #pragma unroll
      for (int kd = 0; kd < 2; ++kd) {
        #pragma unroll
        for (int hw = 0; hw < 4; ++hw) {
          const float v = (float)in[b * sB + (d + kd) * sD + hw * sHW + c];
          const int wi = c * 8 + kd * 4 + hw;
          a0 += v * wl[wi];  a1 += v * wl[C8 + wi];
          c0 += v * wc[wi];  c1 += v * wc[C8 + wi];  c2 += v * wc[2 * C8 + wi];
        }
      }
    }
  }
  #pragma unroll
  for (int off = 32; off; off >>= 1) {
    a0 += __shfl_down(a0, off, 64);
    a1 += __shfl_down(a1, off, 64);
    c0 += __shfl_down(c0, off, 64);
    c1 += __shfl_down(c1, off, 64);
    c2 += __shfl_down(c2, off, 64);
  }
  __shared__ float red[5][4];
  const int lane = tid & 63, wv = tid >> 6;
  if (lane == 0) { red[0][wv] = a0; red[1][wv] = a1; red[2][wv] = c0; red[3][wv] = c1; red[4][wv] = c2; }
  __syncthreads();
  if (tid == 0) {
    float L0 = red[0][0] + red[0][1] + red[0][2] + red[0][3];
    float L1 = red[1][0] + red[1][1] + red[1][2] + red[1][3];
    float F0 = red[2][0] + red[2][1] + red[2][2] + red[2][3];
    float F1 = red[3][0] + red[3][1] + red[3][2] + red[3][3];
    float F2 = red[4][0] + red[4][1] + red[4][2] + red[4][3];
    float* loc = out + (size_t)b * 52 + loff;
    loc[0 * dcnt + d] = L0;
    loc[1 * dcnt + d] = L1;
    float* cf = out + 6656 + (size_t)b * 78 + coff;
    cf[0 * dcnt + d] = F0;
    cf[1 * dcnt + d] = F1;
    cf[2 * dcnt + d] = F2;
  }
}

// shared tail: layer1 + layer2 pipeline reading h1b (linear bf16)
static void tail_layers(bf16* W, bf16* h1b, float* out,
                        const float* e1w1, const float* e1w2,
                        const float* lw2p, const float* cw2p,
                        const float* e2w1, const float* e2w2,
                        const float* lw3, const float* cw3,
                        const float* lw1, const float* cw1,
                        size_t W1c1, size_t h2a, size_t w2p1, size_t h2b,
                        size_t W1c2, size_t h3a, size_t w2p2, size_t h3b,
                        hipStream_t stream) {
  heads_k<bf16, false><<<128 * 7, 256, 0, stream>>>(
      h1b, lw1, cw1, out, 1024, 7, 32768, 4096, 1024, 1, 30, 45);
  hipMemsetAsync(W + h2a, 0, (size_t)786432 * 2, stream);
  cvt_w1<<<128, 256, 0, stream>>>(e1w1, W + W1c1, 32768);
  GP g3 = {h1b, W + W1c1, W + h2a, 1024,
           4, 32768, 3, 8192, 3, 1024,
           4, 6144, 3, 1024, 3, 256, 1024,
           8, 256, 0, 0};
  gemm_bf<1, 1, false><<<dim3(64, 8), 256, 0, stream>>>(g3);
  pack_w2<<<dim3(512, 4), 256, 0, stream>>>(e1w2, W + w2p1, 0, 256);
  GP g4 = {W + h2a, W + w2p1, W + h2b, 3072,
           2, 6144, 0, 0, 3, 1024,
           0, 2048, 0, 0, 0, 0, 0,
           9, 512, 0, 8};
  gemm_bf<1, 1, true><<<dim3(16, 64), 256, 0, stream>>>(g4);
  heads_k<bf16, false><<<128 * 3, 256, 0, stream>>>(
      W + h2b, lw2p, cw2p, out, 512, 3, 8192, 2048, 512, 1, 44, 66);

  hipMemsetAsync(W + h3a, 0, (size_t)262144 * 2, stream);
  cvt_w1<<<32, 256, 0, stream>>>(e2w1, W + W1c2, 8192);
  GP g5 = {W + h2b, W + W1c2, W + h3a, 512,
           3, 8192, 1, 4096, 3, 512,
           3, 2048, 1, 512, 3, 128, 512,
           7, 128, 0, 0};
  gemm_bf<1, 1, false><<<dim3(32, 4), 256, 0, stream>>>(g5);
  pack_w2<<<dim3(256, 2), 256, 0, stream>>>(e2w2, W + w2p2, 0, 128);
  GP g6 = {W + h3a, W + w2p2, W + h3b, 1536,
           1, 2048, 0, 0, 1, 512,
           0, 1024, 0, 0, 0, 0, 0,
           8, 256, 0, 7};
  gemm_bf<1, 1, true><<<dim3(8, 32), 256, 0, stream>>>(g6);
  heads_k<bf16, false><<<128 * 1, 256, 0, stream>>>(
      W + h3b, lw3, cw3, out, 256, 1, 2048, 1024, 256, 1, 50, 75);
}

extern "C" void kernel_launch(void* const* d_in, const int* in_sizes, int n_in,
                              void* d_out, int out_size, void* d_ws, size_t ws_size,
                              hipStream_t stream) {
  (void)in_sizes; (void)n_in; (void)out_size;
  const float* x    = (const float*)d_in[0];
  const float* lw0  = (const float*)d_in[2];
  const float* cw0  = (const float*)d_in[3];
  const float* e0w1 = (const float*)d_in[4];
  const float* e0w2 = (const float*)d_in[5];
  const float* lw1  = (const float*)d_in[6];
  const float* cw1  = (const float*)d_in[7];
  const float* e1w1 = (const float*)d_in[8];
  const float* e1w2 = (const float*)d_in[9];
  const float* lw2  = (const float*)d_in[10];
  const float* cw2  = (const float*)d_in[11];
  const float* e2w1 = (const float*)d_in[12];
  const float* e2w2 = (const float*)d_in[13];
  const float* lw3  = (const float*)d_in[14];
  const float* cw3  = (const float*)d_in[15];
  float* out = (float*)d_out;
  bf16* W = (bf16*)d_ws;

  if (ws_size >= (size_t)49283072) {
    // -------- fast path (r16 champion, g2 -> 2-wave asymmetric) --------
    const size_t xclo = 0;
    const size_t W1f  = 16777216;
    const size_t h1af = 17825792;
    const size_t h1bf = 20447232;
    const size_t w2p0f = 0;
    bf16* Bh = W + h1bf;
    float* P = (float*)(W + h1bf + 131072);

    hipMemsetAsync(W + h1af, 0, (size_t)2621440 * 2, stream);
    pack_x<true><<<dim3(128, 32), 256, 0, stream>>>(x, W + xclo);
    pack_w0<<<512, 256, 0, stream>>>(lw0, cw0, Bh);
    head0_gemm<<<dim3(32, 8), 256, 0, stream>>>(W + xclo, Bh, P);
    head0_combine<<<128, 128, 0, stream>>>(P, out);
    cvt_w1<<<512, 256, 0, stream>>>(e0w1, W + W1f, 131072);

    gemm1b<<<2048, 256, 0, stream>>>(W + xclo, W + W1f, W + h1af);

    pack_w2<<<dim3(1024, 8), 256, 0, stream>>>(e0w2, W + w2p0f, 0, 512);
    gemm2_v2<<<dim3(16, 64), 128, 0, stream>>>(W + h1af, W + w2p0f, W + h1bf);

    tail_layers(W, W + h1bf, out, e1w1, e1w2, lw2, cw2, e2w1, e2w2, lw3, cw3, lw1, cw1,
                0, 262144, 1048576, 4587520, 6684672, 6750208, 7012352, 7897088, stream);
    return;
  }

  // -------- fallback (proven compact layout) --------
  const size_t A0o  = 0;
  const size_t W1o  = 8388608;
  const size_t h1ao = 9437184;
  const size_t h1bo = 12058624;
  const size_t W1c1 = 8388608, W1c2 = 8650752, h3ao = 8716288, h3bo = 8978432;
  const size_t h2ao = 9437184, h2bo = 12058624;
  const size_t w2p0o = 0, w2p1o = 0, w2p2o = 3538944;

  hipMemsetAsync(W + h1ao, 0, (size_t)2621440 * 2, stream);
  pack_x<false><<<dim3(128, 32), 256, 0, stream>>>(x, W + A0o);
  cvt_w1<<<512, 256, 0, stream>>>(e0w1, W + W1o, 131072);

  GP g1 = {W + A0o, W + W1o, W + h1ao, 2048,
           0, 2048, 0, 0, 0, 0,
           5, 20480, 7, 2048, 3, 512, 2048,
           9, 512, 0, 0};
  gemm_bf<2, 2, false><<<dim3(64, 8), 256, 0, stream>>>(g1);

  pack_w2<<<dim3(512, 8), 256, 0, stream>>>(e0w2, W + w2p0o, 0, 512);
  GP g2a = {W + h1ao, W + w2p0o, W + h1bo, 6144,
            3, 20480, 0, 0, 7, 2048,
            0, 4096, 0, 0, 0, 0, 0,
            9, 1024, 0, 9};
  gemm_bf<2, 2, true><<<dim3(16, 32), 256, 0, stream>>>(g2a);
  pack_w2<<<dim3(512, 8), 256, 0, stream>>>(e0w2, W + w2p0o, 512, 512);
  GP g2b = {W + h1ao, W + w2p0o, W + h1bo, 6144,
            3, 20480, 0, 0, 7, 2048,
            0, 4096, 0, 0, 0, 0, 0,
            9, 1024, 512, 9};
  gemm_bf<2, 2, true><<<dim3(16, 32), 256, 0, stream>>>(g2b);

  heads_k<bf16, false><<<128 * 7, 256, 0, stream>>>(
      W + h1bo, lw1, cw1, out, 1024, 7, 32768, 4096, 1024, 1, 30, 45);

  hipMemsetAsync(W + h2ao, 0, (size_t)786432 * 2, stream);
  cvt_w1<<<128, 256, 0, stream>>>(e1w1, W + W1c1, 32768);
  GP g3 = {W + h1bo, W + W1c1, W + h2ao, 1024,
           4, 32768, 3, 8192, 3, 1024,
           4, 6144, 3, 1024, 3, 256, 1024,
           8, 256, 0, 0};
  gemm_bf<1, 1, false><<<dim3(64, 8), 256, 0, stream>>>(g3);
  pack_w2<<<dim3(512, 4), 256, 0, stream>>>(e1w2, W + w2p1o, 0, 256);
  GP g4 = {W + h2ao, W + w2p1o, W + h2bo, 3072,
           2, 6144, 0, 0, 3, 1024,
           0, 2048, 0, 0, 0, 0, 0,
           9, 512, 0, 8};
  gemm_bf<1, 1, true><<<dim3(16, 64), 256, 0, stream>>>(g4);
  heads_k<bf16, false><<<128 * 3, 256, 0, stream>>>(
      W + h2bo, lw2, cw2, out, 512, 3, 8192, 2048, 512, 1, 44, 66);

  hipMemsetAsync(W + h3ao, 0, (size_t)262144 * 2, stream);
  cvt_w1<<<32, 256, 0, stream>>>(e2w1, W + W1c2, 8192);
  GP g5 = {W + h2bo, W + W1c2, W + h3ao, 512,
           3, 8192, 1, 4096, 3, 512,
           3, 2048, 1, 512, 3, 128, 512,
           7, 128, 0, 0};
  gemm_bf<1, 1, false><<<dim3(32, 4), 256, 0, stream>>>(g5);
  pack_w2<<<dim3(256, 2), 256, 0, stream>>>(e2w2, W + w2p2o, 0, 128);
  GP g6 = {W + h3ao, W + w2p2o, W + h3bo, 1536,
           1, 2048, 0, 0, 1, 512,
           0, 1024, 0, 0, 0, 0, 0,
           8, 256, 0, 7};
  gemm_bf<1, 1, true><<<dim3(8, 32), 256, 0, stream>>>(g6);
  heads_k<bf16, false><<<128 * 1, 256, 0, stream>>>(
      W + h3bo, lw3, cw3, out, 256, 1, 2048, 1024, 256, 1, 50, 75);

  heads_k<float, true><<<128 * 15, 256, 0, stream>>>(
      x, lw0, cw0, out, 2048, 15, 131072, 4, 1, 64, 0, 0);
}

// Round 18
// 234.253 us; speedup vs baseline: 1.0078x; 1.0078x over previous
//
#include <hip/hip_runtime.h>

typedef __bf16 bf16;
typedef bf16 bf16x2 __attribute__((ext_vector_type(2)));
typedef bf16 bf16x8 __attribute__((ext_vector_type(8)));
typedef float f32x4 __attribute__((ext_vector_type(4)));

__device__ __forceinline__ void gload16(const bf16* g, bf16* l) {
  __builtin_amdgcn_global_load_lds((const __attribute__((address_space(1))) void*)g,
                                   (__attribute__((address_space(3))) void*)l, 16, 0, 0);
}

// ---------- pack x [128][2048][16][4] f32 -> bf16 channel-last ----------
template <bool FULL>
__global__ __launch_bounds__(256) void pack_x(const float* __restrict__ x, bf16* __restrict__ dstbuf) {
  __shared__ float tile[64 * 65];
  const int b = blockIdx.x, cb = blockIdx.y;
  const int t = threadIdx.x;
  const float* src = x + ((size_t)b * 2048 + cb * 64) * 64;
  #pragma unroll
  for (int p = 0; p < 16; ++p) {
    int idx = t + p * 256;
    tile[(idx >> 6) * 65 + (idx & 63)] = src[idx];
  }
  __syncthreads();
  if constexpr (FULL) {
    bf16* dst = dstbuf + (size_t)b * 131072 + cb * 64;
    #pragma unroll
    for (int p = 0; p < 8; ++p) {
      int idx = t + p * 256;
      int dhw = idx >> 5;
      int cl2 = (idx & 31) * 2;
      bf16x2 v;
      v.x = (bf16)tile[cl2 * 65 + dhw];
      v.y = (bf16)tile[(cl2 + 1) * 65 + dhw];
      *(bf16x2*)(dst + (size_t)dhw * 2048 + cl2) = v;
    }
  } else {
    bf16* dst = dstbuf + ((size_t)b * 32) * 2048 + cb * 64;
    const int cl2 = (t & 31) * 2, mr0 = t >> 5;
    #pragma unroll
    for (int p = 0; p < 4; ++p) {
      int mrow = mr0 + p * 8;
      int dd = mrow >> 2, hw = mrow & 3;
      int sdhw = dd * 8 + hw;
      bf16x2 v;
      v.x = (bf16)tile[cl2 * 65 + sdhw];
      v.y = (bf16)tile[(cl2 + 1) * 65 + sdhw];
      *(bf16x2*)(dst + (size_t)mrow * 2048 + cl2) = v;
    }
  }
}

// ---------- head0 weights -> Bh [16][8192] bf16 ----------
__global__ __launch_bounds__(256) void pack_w0(const float* __restrict__ lw0,
                                               const float* __restrict__ cw0,
                                               bf16* __restrict__ Bh) {
  int idx = blockIdx.x * 256 + threadIdx.x;
  int n = idx >> 13, k = idx & 8191;
  int hw = k >> 11, c = k & 2047;
  float v = 0.f;
  if (n < 10) {
    int kd = n / 5, j = n % 5;
    const float* w = (j < 2) ? (lw0 + j * 16384) : (cw0 + (j - 2) * 16384);
    v = w[c * 8 + kd * 4 + hw];
  }
  Bh[idx] = (bf16)v;
}

// ---------- head0 GEMM: M=2048, N=16, K=8192, split-K 8 ----------
__global__ __launch_bounds__(256) void head0_gemm(const bf16* __restrict__ xcl,
                                                  const bf16* __restrict__ Bh,
                                                  float* __restrict__ P) {
  __shared__ bf16 ldsA[64 * 64];
  __shared__ bf16 ldsB[16 * 64];
  const int bm = blockIdx.x, ks = blockIdx.y;
  const int tid = threadIdx.x;
  const int wv = tid >> 6, lane = tid & 63, r = lane & 15, g = lane >> 4;
  f32x4 acc = {0.f, 0.f, 0.f, 0.f};
  for (int k0 = 0; k0 < 1024; k0 += 64) {
    #pragma unroll
    for (int q = 0; q < 2; ++q) {
      int idx = tid + q * 256;
      int row = idx >> 3, cg = idx & 7;
      gload16(xcl + (size_t)(bm * 64 + row) * 8192 + ks * 1024 + k0 + (cg ^ (row & 7)) * 8,
              ldsA + idx * 8);
    }
    if (tid < 128) {
      int row = tid >> 3, cg = tid & 7;
      gload16(Bh + (size_t)row * 8192 + ks * 1024 + k0 + (cg ^ (row & 7)) * 8,
              ldsB + tid * 8);
    }
    __syncthreads();
    #pragma unroll
    for (int ks2 = 0; ks2 < 2; ++ks2) {
      int rowa = wv * 16 + r;
      bf16x8 af = *(const bf16x8*)(ldsA + rowa * 64 + ((ks2 * 4 + g) ^ (rowa & 7)) * 8);
      bf16x8 bf_ = *(const bf16x8*)(ldsB + r * 64 + ((ks2 * 4 + g) ^ (r & 7)) * 8);
      acc = __builtin_amdgcn_mfma_f32_16x16x32_bf16(af, bf_, acc, 0, 0, 0);
    }
    __syncthreads();
  }
  const int m = bm * 64 + wv * 16 + g * 4;
  #pragma unroll
  for (int jr = 0; jr < 4; ++jr)
    P[(size_t)(ks * 2048 + m + jr) * 16 + r] = acc[jr];
}

// ---------- head0 combine ----------
__global__ __launch_bounds__(128) void head0_combine(const float* __restrict__ P,
                                                     float* __restrict__ out) {
  const int b = blockIdx.x, t = threadIdx.x;
  if (t < 75) {
    int j = t / 15, d = t % 15;
    float s = 0.f;
    #pragma unroll
    for (int ks = 0; ks < 8; ++ks) {
      const float* pb = P + (size_t)(ks * 2048 + b * 16) * 16;
      s += pb[d * 16 + j] + pb[(d + 1) * 16 + 5 + j];
    }
    if (j < 2) out[b * 52 + j * 15 + d] = s;
    else       out[6656 + b * 78 + (j - 2) * 15 + d] = s;
  }
}

// ---------- f32 -> bf16 flat convert ----------
__global__ __launch_bounds__(256) void cvt_w1(const float* __restrict__ in, bf16* __restrict__ out, int n8) {
  int i = blockIdx.x * 256 + threadIdx.x;
  if (i < n8) {
    const float4* p = (const float4*)(in + (size_t)i * 8);
    float4 a = p[0], b = p[1];
    bf16x8 v = {(bf16)a.x, (bf16)a.y, (bf16)a.z, (bf16)a.w,
                (bf16)b.x, (bf16)b.y, (bf16)b.z, (bf16)b.w};
    *(bf16x8*)(out + (size_t)i * 8) = v;
  }
}

// ---------- w2 [cout][cin][27] f32 -> w2p [oCnt][27][cin] bf16 ----------
__global__ __launch_bounds__(256) void pack_w2(const float* __restrict__ w2, bf16* __restrict__ w2p,
                                               int oBase, int cin) {
  __shared__ float tile[64 * 27];
  const int orel = blockIdx.x, cb = blockIdx.y;
  const int o = oBase + orel;
  const float* src = w2 + ((size_t)o * cin + cb * 64) * 27;
  const int t = threadIdx.x;
  for (int idx = t; idx < 1728; idx += 256) tile[idx] = src[idx];
  __syncthreads();
  bf16* dst = w2p + (size_t)orel * 27 * cin + cb * 64;
  for (int idx = t; idx < 1728; idx += 256) {
    int tap = idx >> 6, cl = idx & 63;
    dst[(size_t)tap * cin + cl] = (bf16)tile[cl * 27 + tap];
  }
}

// ---------- generic bf16 MFMA GEMM (BK=64, scalarized W2M, proven) ----------
struct GP {
  const bf16* A; const bf16* B; bf16* O;
  int K;
  int ashb, asB, am1, as1, am2, as2;
  int oshb, osB, om1, os1, om2, os2, oOff;
  int lgCv, coutS, oCol0, lgCin;
};

template <int FM, int FN, bool W2M>
__global__ __launch_bounds__(256) void gemm_bf(GP p) {
  constexpr int BM = FM * 32, BN = FN * 32;
  __shared__ bf16 lds[(BM + BN) * 64];
  bf16* ldsA = lds;
  bf16* ldsB = lds + BM * 64;
  const int tid = threadIdx.x;
  const int bm = blockIdx.x, bn = blockIdx.y;

  int aBase[BM / 32], aL[BM / 32];
  #pragma unroll
  for (int q = 0; q < BM / 32; ++q) {
    int idx = tid + q * 256;
    int row = idx >> 3, cg = idx & 7;
    int m = bm * BM + row;
    aBase[q] = (m >> p.ashb) * p.asB + ((m >> 2) & p.am1) * p.as1 + (m & p.am2) * p.as2;
    aL[q] = ((cg ^ row) & 7) * 8;
  }
  int opk[BN / 32];
  int bN[BN / 32], bL[BN / 32];
  int khkw0 = 0, khkw1 = 0, khkw2 = 0, khkw3 = 0;
  #pragma unroll
  for (int q = 0; q < BN / 32; ++q) {
    int idx = tid + q * 256;
    int row = idx >> 3, cg = idx & 7;
    int n = bn * BN + row;
    int sw = ((cg ^ row) & 7) * 8;
    if constexpr (W2M) {
      int op = n & ((1 << p.lgCv) - 1);
      opk[q] = (op * 27 << p.lgCin) + sw;
      bN[q] = 0; bL[q] = 0;
    } else {
      bN[q] = n; bL[q] = sw; opk[q] = 0;
    }
  }
  if constexpr (W2M) {
    const int hwp = (bn * BN) >> p.lgCv;
    const int hp = hwp >> 1, wp = hwp & 1;
    khkw0 = ((1 - hp) * 3 + (1 - wp)) << p.lgCin;
    khkw1 = ((1 - hp) * 3 + (2 - wp)) << p.lgCin;
    khkw2 = ((2 - hp) * 3 + (1 - wp)) << p.lgCin;
    khkw3 = ((2 - hp) * 3 + (2 - wp)) << p.lgCin;
  }

  const int wv = tid >> 6, wm = wv >> 1, wn = wv & 1;
  const int lane = tid & 63, r = lane & 15, g = lane >> 4;

  f32x4 acc[FM][FN];
  const f32x4 zz = {0.f, 0.f, 0.f, 0.f};
  #pragma unroll
  for (int i = 0; i < FM; ++i)
    #pragma unroll
    for (int j = 0; j < FN; ++j) acc[i][j] = zz;

  for (int k0 = 0; k0 < p.K; k0 += 64) {
    #pragma unroll
    for (int q = 0; q < BM / 32; ++q) {
      int idx = tid + q * 256;
      gload16(p.A + aBase[q] + k0 + aL[q], ldsA + idx * 8);
    }
    if constexpr (W2M) {
      const int kd = k0 >> (p.lgCin + 2);
      const int hwsel = (k0 >> p.lgCin) & 3;
      const int c0 = k0 & ((1 << p.lgCin) - 1);
      int kk = (hwsel & 2) ? ((hwsel & 1) ? khkw3 : khkw2)
                           : ((hwsel & 1) ? khkw1 : khkw0);
      const int koff = (kd * 9 << p.lgCin) + kk + c0;
      #pragma unroll
      for (int q = 0; q < BN / 32; ++q) {
        int idx = tid + q * 256;
        gload16(p.B + opk[q] + koff, ldsB + idx * 8);
      }
    } else {
      #pragma unroll
      for (int q = 0; q < BN / 32; ++q) {
        int idx = tid + q * 256;
        gload16(p.B + (size_t)bN[q] * p.K + k0 + bL[q], ldsB + idx * 8);
      }
    }
    __syncthreads();
    #pragma unroll
    for (int ks = 0; ks < 2; ++ks) {
      bf16x8 af[FM], bfr[FN];
      #pragma unroll
      for (int i = 0; i < FM; ++i) {
        int row = wm * FM * 16 + i * 16 + r;
        int pcg = (ks * 4 + g) ^ (row & 7);
        af[i] = *(const bf16x8*)(ldsA + row * 64 + pcg * 8);
      }
      #pragma unroll
      for (int j = 0; j < FN; ++j) {
        int row = wn * FN * 16 + j * 16 + r;
        int pcg = (ks * 4 + g) ^ (row & 7);
        bfr[j] = *(const bf16x8*)(ldsB + row * 64 + pcg * 8);
      }
      #pragma unroll
      for (int i = 0; i < FM; ++i)
        #pragma unroll
        for (int j = 0; j < FN; ++j)
          acc[i][j] = __builtin_amdgcn_mfma_f32_16x16x32_bf16(af[i], bfr[j], acc[i][j], 0, 0, 0);
    }
    __syncthreads();
  }

  #pragma unroll
  for (int i = 0; i < FM; ++i) {
    #pragma unroll
    for (int j = 0; j < FN; ++j) {
      int ncol = bn * BN + wn * FN * 16 + j * 16 + r;
      int outcol = (ncol >> p.lgCv) * p.coutS + p.oCol0 + (ncol & ((1 << p.lgCv) - 1));
      #pragma unroll
      for (int jr = 0; jr < 4; ++jr) {
        int m = bm * BM + wm * FM * 16 + i * 16 + g * 4 + jr;
        int oa = (m >> p.oshb) * p.osB + ((m >> 2) & p.om1) * p.os1 + (m & p.om2) * p.os2 + p.oOff + outcol;
        p.O[oa] = (bf16)acc[i][j][jr];
      }
    }
  }
}

// ---------- g1: 32^2 tile, 2048 blocks = 8/CU, XCD-sliced along M (r16) ----------
__global__ __launch_bounds__(256) void gemm1b(const bf16* __restrict__ A,
                                              const bf16* __restrict__ B,
                                              bf16* __restrict__ O) {
  __shared__ bf16 lds[4096];
  bf16* ldsA = lds;
  bf16* ldsB = lds + 2048;
  const int tid = threadIdx.x;
  const int id = blockIdx.x;
  const int s = id >> 3;
  const int bm = (id & 7) * 16 + (s & 15);
  const int bn = s >> 4;

  const int row = tid >> 3, cg = tid & 7;
  const int sw = ((cg ^ row) & 7) * 8;
  const int m0 = bm * 32 + row;
  const int aOff = (m0 >> 5) * 131072 + ((m0 >> 2) & 7) * 16384 + (m0 & 3) * 2048 + sw;
  const int n0 = bn * 32 + row;
  const int bOff = n0 * 2048 + sw;

  const int wv = tid >> 6, wm = wv >> 1, wn = wv & 1;
  const int lane = tid & 63, r = lane & 15, g = lane >> 4;

  f32x4 acc = {0.f, 0.f, 0.f, 0.f};

  for (int k0 = 0; k0 < 2048; k0 += 64) {
    gload16(A + aOff + k0, ldsA + tid * 8);
    gload16(B + bOff + k0, ldsB + tid * 8);
    __syncthreads();
    #pragma unroll
    for (int ks = 0; ks < 2; ++ks) {
      int rowa = wm * 16 + r;
      int rowb = wn * 16 + r;
      bf16x8 af = *(const bf16x8*)(ldsA + rowa * 64 + (((ks * 4 + g) ^ rowa) & 7) * 8);
      bf16x8 bf_ = *(const bf16x8*)(ldsB + rowb * 64 + (((ks * 4 + g) ^ rowb) & 7) * 8);
      acc = __builtin_amdgcn_mfma_f32_16x16x32_bf16(af, bf_, acc, 0, 0, 0);
    }
    __syncthreads();
  }

  const int col = bn * 32 + wn * 16 + r;
  #pragma unroll
  for (int jr = 0; jr < 4; ++jr) {
    int m = bm * 32 + wm * 16 + g * 4 + jr;
    int oa = (m >> 5) * 20480 + ((m >> 2) & 7) * 2048 + (m & 3) * 512 + 2048 + col;
    O[oa] = (bf16)acc[jr];
  }
}

// ---------- g2 XCD-swizzled 64^2 (r12 champion) ----------
__global__ __launch_bounds__(256) void gemm2_swz(const bf16* __restrict__ A,
                                                 const bf16* __restrict__ B,
                                                 bf16* __restrict__ O) {
  __shared__ bf16 lds[8192];
  bf16* ldsA = lds;
  bf16* ldsB = lds + 4096;
  const int tid = threadIdx.x;
  const int id = blockIdx.x + (blockIdx.y << 4);
  const int s = id >> 3;
  const int bn = (id & 7) * 8 + (s & 7);
  const int bm = s >> 3;

  int aOff[2], bOff[2];
  #pragma unroll
  for (int q = 0; q < 2; ++q) {
    int idx = tid + q * 256;
    int row = idx >> 3, cg = idx & 7;
    int sw = ((cg ^ row) & 7) * 8;
    int m = bm * 64 + row;
    aOff[q] = (m >> 3) * 20480 + (m & 7) * 2048 + sw;
    int n = bn * 64 + row;
    bOff[q] = (n & 1023) * 13824 + sw;
  }
  const int hwp = (bn * 64) >> 10;
  const int hp = hwp >> 1, wp = hwp & 1;
  const int kk0 = ((1 - hp) * 3 + (1 - wp)) << 9;
  const int kk1 = ((1 - hp) * 3 + (2 - wp)) << 9;
  const int kk2 = ((2 - hp) * 3 + (1 - wp)) << 9;
  const int kk3 = ((2 - hp) * 3 + (2 - wp)) << 9;

  const int wv = tid >> 6, wm = wv >> 1, wn = wv & 1;
  const int lane = tid & 63, r = lane & 15, g = lane >> 4;

  f32x4 acc[2][2];
  const f32x4 zz = {0.f, 0.f, 0.f, 0.f};
  #pragma unroll
  for (int i = 0; i < 2; ++i)
    #pragma unroll
    for (int j = 0; j < 2; ++j) acc[i][j] = zz;

  for (int k0 = 0; k0 < 6144; k0 += 64) {
    int kd = k0 >> 11, hws = (k0 >> 9) & 3, c0 = k0 & 511;
    int kk = (hws & 2) ? ((hws & 1) ? kk3 : kk2) : ((hws & 1) ? kk1 : kk0);
    int koff = kd * 4608 + kk + c0;
    #pragma unroll
    for (int q = 0; q < 2; ++q) {
      int idx = tid + q * 256;
      gload16(A + aOff[q] + k0, ldsA + idx * 8);
      gload16(B + bOff[q] + koff, ldsB + idx * 8);
    }
    __syncthreads();
    #pragma unroll
    for (int ks = 0; ks < 2; ++ks) {
      bf16x8 af[2], bfr[2];
      #pragma unroll
      for (int i = 0; i < 2; ++i) {
        int row = wm * 32 + i * 16 + r;
        int pcg = (ks * 4 + g) ^ (row & 7);
        af[i] = *(const bf16x8*)(ldsA + row * 64 + pcg * 8);
      }
      #pragma unroll
      for (int j = 0; j < 2; ++j) {
        int row = wn * 32 + j * 16 + r;
        int pcg = (ks * 4 + g) ^ (row & 7);
        bfr[j] = *(const bf16x8*)(ldsB + row * 64 + pcg * 8);
      }
      #pragma unroll
      for (int i = 0; i < 2; ++i)
        #pragma unroll
        for (int j = 0; j < 2; ++j)
          acc[i][j] = __builtin_amdgcn_mfma_f32_16x16x32_bf16(af[i], bfr[j], acc[i][j], 0, 0, 0);
    }
    __syncthreads();
  }

  #pragma unroll
  for (int i = 0; i < 2; ++i) {
    #pragma unroll
    for (int j = 0; j < 2; ++j) {
      int col = bn * 64 + wn * 32 + j * 16 + r;
      #pragma unroll
      for (int jr = 0; jr < 4; ++jr) {
        int rw = bm * 64 + wm * 32 + i * 16 + g * 4 + jr;
        O[(size_t)rw * 4096 + col] = (bf16)acc[i][j][jr];
      }
    }
  }
}

// ---------- detection heads: kernel (2,2,2) VALID ----------
template <typename T, bool XL>
__global__ __launch_bounds__(256)
void heads_k(const T* __restrict__ in, const float* __restrict__ wl,
             const float* __restrict__ wc, float* __restrict__ out,
             const int C, const int dcnt, const int sB, const int sD,
             const int sHW, const int sC, const int loff, const int coff) {
  const int tid = threadIdx.x;
  const int blk = blockIdx.x;
  const int b = blk / dcnt, d = blk - b * dcnt;
  float a0 = 0, a1 = 0, c0 = 0, c1 = 0, c2 = 0;
  const int C8 = C * 8;
  if constexpr (XL) {
    const int hw = tid & 3, kd = (tid >> 2) & 1, cb = tid >> 3;
    const int base = b * sB + (d + kd) * sD + hw * sHW;
    const int wb = kd * 4 + hw;
    for (int i = 0; i < C / 32; ++i) {
      const int c = cb + i * 32;
      const float v = (float)in[base + c * sC];
      const int wi = c * 8 + wb;
      a0 += v * wl[wi];  a1 += v * wl[C8 + wi];
      c0 += v * wc[wi];  c1 += v * wc[C8 + wi];  c2 += v * wc[2 * C8 + wi];
    }
  } else {
    for (int c = tid; c < C; c += 256) {
      #pragma unroll
      for (int kd = 0; kd < 2; ++kd) {
        #pragma unroll
        for (int hw = 0; hw < 4; ++hw) {
          const float v = (float)in[b * sB + (d + kd) * sD + hw * sHW + c];
          const int wi = c * 8 + kd * 4 + hw;
          a0 += v * wl[wi];  a1 += v * wl[C8 + wi];
          c0 += v * wc[wi];  c1 += v * wc[C8 + wi];  c2 += v * wc[2 * C8 + wi];
        }
      }
    }
  }
  #pragma unroll
  for (int off = 32; off; off >>= 1) {
    a0 += __shfl_down(a0, off, 64);
    a1 += __shfl_down(a1, off, 64);
    c0 += __shfl_down(c0, off, 64);
    c1 += __shfl_down(c1, off, 64);
    c2 += __shfl_down(c2, off, 64);
  }
  __shared__ float red[5][4];
  const int lane = tid & 63, wv = tid >> 6;
  if (lane == 0) { red[0][wv] = a0; red[1][wv] = a1; red[2][wv] = c0; red[3][wv] = c1; red[4][wv] = c2; }
  __syncthreads();
  if (tid == 0) {
    float L0 = red[0][0] + red[0][1] + red[0][2] + red[0][3];
    float L1 = red[1][0] + red[1][1] + red[1][2] + red[1][3];
    float F0 = red[2][0] + red[2][1] + red[2][2] + red[2][3];
    float F1 = red[3][0] + red[3][1] + red[3][2] + red[3][3];
    float F2 = red[4][0] + red[4][1] + red[4][2] + red[4][3];
    float* loc = out + (size_t)b * 52 + loff;
    loc[0 * dcnt + d] = L0;
    loc[1 * dcnt + d] = L1;
    float* cf = out + 6656 + (size_t)b * 78 + coff;
    cf[0 * dcnt + d] = F0;
    cf[1 * dcnt + d] = F1;
    cf[2 * dcnt + d] = F2;
  }
}

// shared tail: layer1 + layer2 pipeline reading h1b (linear bf16)
static void tail_layers(bf16* W, bf16* h1b, float* out,
                        const float* e1w1, const float* e1w2,
                        const float* lw2p, const float* cw2p,
                        const float* e2w1, const float* e2w2,
                        const float* lw3, const float* cw3,
                        const float* lw1, const float* cw1,
                        size_t W1c1, size_t h2a, size_t w2p1, size_t h2b,
                        size_t W1c2, size_t h3a, size_t w2p2, size_t h3b,
                        hipStream_t stream) {
  heads_k<bf16, false><<<128 * 7, 256, 0, stream>>>(
      h1b, lw1, cw1, out, 1024, 7, 32768, 4096, 1024, 1, 30, 45);
  hipMemsetAsync(W + h2a, 0, (size_t)786432 * 2, stream);
  cvt_w1<<<128, 256, 0, stream>>>(e1w1, W + W1c1, 32768);
  GP g3 = {h1b, W + W1c1, W + h2a, 1024,
           4, 32768, 3, 8192, 3, 1024,
           4, 6144, 3, 1024, 3, 256, 1024,
           8, 256, 0, 0};
  gemm_bf<1, 1, false><<<dim3(64, 8), 256, 0, stream>>>(g3);
  pack_w2<<<dim3(512, 4), 256, 0, stream>>>(e1w2, W + w2p1, 0, 256);
  GP g4 = {W + h2a, W + w2p1, W + h2b, 3072,
           2, 6144, 0, 0, 3, 1024,
           0, 2048, 0, 0, 0, 0, 0,
           9, 512, 0, 8};
  gemm_bf<1, 1, true><<<dim3(16, 64), 256, 0, stream>>>(g4);
  heads_k<bf16, false><<<128 * 3, 256, 0, stream>>>(
      W + h2b, lw2p, cw2p, out, 512, 3, 8192, 2048, 512, 1, 44, 66);

  hipMemsetAsync(W + h3a, 0, (size_t)262144 * 2, stream);
  cvt_w1<<<32, 256, 0, stream>>>(e2w1, W + W1c2, 8192);
  GP g5 = {W + h2b, W + W1c2, W + h3a, 512,
           3, 8192, 1, 4096, 3, 512,
           3, 2048, 1, 512, 3, 128, 512,
           7, 128, 0, 0};
  gemm_bf<1, 1, false><<<dim3(32, 4), 256, 0, stream>>>(g5);
  pack_w2<<<dim3(256, 2), 256, 0, stream>>>(e2w2, W + w2p2, 0, 128);
  GP g6 = {W + h3a, W + w2p2, W + h3b, 1536,
           1, 2048, 0, 0, 1, 512,
           0, 1024, 0, 0, 0, 0, 0,
           8, 256, 0, 7};
  gemm_bf<1, 1, true><<<dim3(8, 32), 256, 0, stream>>>(g6);
  heads_k<bf16, false><<<128 * 1, 256, 0, stream>>>(
      W + h3b, lw3, cw3, out, 256, 1, 2048, 1024, 256, 1, 50, 75);
}

extern "C" void kernel_launch(void* const* d_in, const int* in_sizes, int n_in,
                              void* d_out, int out_size, void* d_ws, size_t ws_size,
                              hipStream_t stream) {
  (void)in_sizes; (void)n_in; (void)out_size;
  const float* x    = (const float*)d_in[0];
  const float* lw0  = (const float*)d_in[2];
  const float* cw0  = (const float*)d_in[3];
  const float* e0w1 = (const float*)d_in[4];
  const float* e0w2 = (const float*)d_in[5];
  const float* lw1  = (const float*)d_in[6];
  const float* cw1  = (const float*)d_in[7];
  const float* e1w1 = (const float*)d_in[8];
  const float* e1w2 = (const float*)d_in[9];
  const float* lw2  = (const float*)d_in[10];
  const float* cw2  = (const float*)d_in[11];
  const float* e2w1 = (const float*)d_in[12];
  const float* e2w2 = (const float*)d_in[13];
  const float* lw3  = (const float*)d_in[14];
  const float* cw3  = (const float*)d_in[15];
  float* out = (float*)d_out;
  bf16* W = (bf16*)d_ws;

  if (ws_size >= (size_t)49283072) {
    // -------- fast path (r16 champion structure) --------
    const size_t xclo = 0;
    const size_t W1f  = 16777216;
    const size_t h1af = 17825792;
    const size_t h1bf = 20447232;
    const size_t w2p0f = 0;
    bf16* Bh = W + h1bf;
    float* P = (float*)(W + h1bf + 131072);

    hipMemsetAsync(W + h1af, 0, (size_t)2621440 * 2, stream);
    pack_x<true><<<dim3(128, 32), 256, 0, stream>>>(x, W + xclo);
    pack_w0<<<512, 256, 0, stream>>>(lw0, cw0, Bh);
    head0_gemm<<<dim3(32, 8), 256, 0, stream>>>(W + xclo, Bh, P);
    head0_combine<<<128, 128, 0, stream>>>(P, out);
    cvt_w1<<<512, 256, 0, stream>>>(e0w1, W + W1f, 131072);

    gemm1b<<<2048, 256, 0, stream>>>(W + xclo, W + W1f, W + h1af);

    pack_w2<<<dim3(1024, 8), 256, 0, stream>>>(e0w2, W + w2p0f, 0, 512);
    gemm2_swz<<<dim3(16, 64), 256, 0, stream>>>(W + h1af, W + w2p0f, W + h1bf);

    tail_layers(W, W + h1bf, out, e1w1, e1w2, lw2, cw2, e2w1, e2w2, lw3, cw3, lw1, cw1,
                0, 262144, 1048576, 4587520, 6684672, 6750208, 7012352, 7897088, stream);
    return;
  }

  // -------- fallback (proven compact layout) --------
  const size_t A0o  = 0;
  const size_t W1o  = 8388608;
  const size_t h1ao = 9437184;
  const size_t h1bo = 12058624;
  const size_t W1c1 = 8388608, W1c2 = 8650752, h3ao = 8716288, h3bo = 8978432;
  const size_t h2ao = 9437184, h2bo = 12058624;
  const size_t w2p0o = 0, w2p1o = 0, w2p2o = 3538944;

  hipMemsetAsync(W + h1ao, 0, (size_t)2621440 * 2, stream);
  pack_x<false><<<dim3(128, 32), 256, 0, stream>>>(x, W + A0o);
  cvt_w1<<<512, 256, 0, stream>>>(e0w1, W + W1o, 131072);

  GP g1 = {W + A0o, W + W1o, W + h1ao, 2048,
           0, 2048, 0, 0, 0, 0,
           5, 20480, 7, 2048, 3, 512, 2048,
           9, 512, 0, 0};
  gemm_bf<2, 2, false><<<dim3(64, 8), 256, 0, stream>>>(g1);

  pack_w2<<<dim3(512, 8), 256, 0, stream>>>(e0w2, W + w2p0o, 0, 512);
  GP g2a = {W + h1ao, W + w2p0o, W + h1bo, 6144,
            3, 20480, 0, 0, 7, 2048,
            0, 4096, 0, 0, 0, 0, 0,
            9, 1024, 0, 9};
  gemm_bf<2, 2, true><<<dim3(16, 32), 256, 0, stream>>>(g2a);
  pack_w2<<<dim3(512, 8), 256, 0, stream>>>(e0w2, W + w2p0o, 512, 512);
  GP g2b = {W + h1ao, W + w2p0o, W + h1bo, 6144,
            3, 20480, 0, 0, 7, 2048,
            0, 4096, 0, 0, 0, 0, 0,
            9, 1024, 512, 9};
  gemm_bf<2, 2, true><<<dim3(16, 32), 256, 0, stream>>>(g2b);

  heads_k<bf16, false><<<128 * 7, 256, 0, stream>>>(
      W + h1bo, lw1, cw1, out, 1024, 7, 32768, 4096, 1024, 1, 30, 45);

  hipMemsetAsync(W + h2ao, 0, (size_t)786432 * 2, stream);
  cvt_w1<<<128, 256, 0, stream>>>(e1w1, W + W1c1, 32768);
  GP g3 = {W + h1bo, W + W1c1, W + h2ao, 1024,
           4, 32768, 3, 8192, 3, 1024,
           4, 6144, 3, 1024, 3, 256, 1024,
           8, 256, 0, 0};
  gemm_bf<1, 1, false><<<dim3(64, 8), 256, 0, stream>>>(g3);
  pack_w2<<<dim3(512, 4), 256, 0, stream>>>(e1w2, W + w2p1o, 0, 256);
  GP g4 = {W + h2ao, W + w2p1o, W + h2bo, 3072,
           2, 6144, 0, 0, 3, 1024,
           0, 2048, 0, 0, 0, 0, 0,
           9, 512, 0, 8};
  gemm_bf<1, 1, true><<<dim3(16, 64), 256, 0, stream>>>(g4);
  heads_k<bf16, false><<<128 * 3, 256, 0, stream>>>(
      W + h2bo, lw2, cw2, out, 512, 3, 8192, 2048, 512, 1, 44, 66);

  hipMemsetAsync(W + h3ao, 0, (size_t)262144 * 2, stream);
  cvt_w1<<<32, 256, 0, stream>>>(e2w1, W + W1c2, 8192);
  GP g5 = {W + h2bo, W + W1c2, W + h3ao, 512,
           3, 8192, 1, 4096, 3, 512,
           3, 2048, 1, 512, 3, 128, 512,
           7, 128, 0, 0};
  gemm_bf<1, 1, false><<<dim3(32, 4), 256, 0, stream>>>(g5);
  pack_w2<<<dim3(256, 2), 256, 0, stream>>>(e2w2, W + w2p2o, 0, 128);
  GP g6 = {W + h3ao, W + w2p2o, W + h3bo, 1536,
           1, 2048, 0, 0, 1, 512,
           0, 1024, 0, 0, 0, 0, 0,
           8, 256, 0, 7};
  gemm_bf<1, 1, true><<<dim3(8, 32), 256, 0, stream>>>(g6);
  heads_k<bf16, false><<<128 * 1, 256, 0, stream>>>(
      W + h3bo, lw3, cw3, out, 256, 1, 2048, 1024, 256, 1, 50, 75);

  heads_k<float, true><<<128 * 15, 256, 0, stream>>>(
      x, lw0, cw0, out, 2048, 15, 131072, 4, 1, 64, 0, 0);
}